// Round 3
// baseline (180.432 us; speedup 1.0000x reference)
//
#include <hip/hip_runtime.h>

// out[b][j] = x[b][(j - s_b) mod T]
//
// LDS-realign, deep-MLP version: each block handles CHUNK=4080 consecutive
// output floats of one row. Staging issues 4 independent 16B-aligned float4
// loads per thread BEFORE any wait (4 outstanding vmem/wave -> latency
// hidden), stores into a +1-float-per-4 padded LDS layout (stride 5 mod 32 =>
// 2-way aliasing, free), one barrier, then 4 realigned float4 stores/thread.

#define CHUNK 4080             // floats per block; mult of 4; (CHUNK/4+1) <= 4*256
#define NITER 4                // unrolled vec4 iterations per thread

__device__ __forceinline__ int pad(int i) { return i + (i >> 2); }

__global__ __launch_bounds__(256) void roll_rows_lds(
    const float* __restrict__ x,
    const int* __restrict__ shifts,
    float* __restrict__ out,
    int T) {
    // staged floats <= CHUNK + 4; padded size pad(CHUNK+4) + margin
    __shared__ float lds[5120];

    const int b = blockIdx.y;
    const int chunk0 = blockIdx.x * CHUNK;   // first output column of block
    const int t = threadIdx.x;

    int s = shifts[b] % T;
    if (s < 0) s += T;

    const int nOut = min(CHUNK, T - chunk0);    // floats this block writes (mult of 4)
    const int base = chunk0 - s;                 // first source float needed
    const int off = base & 3;                    // misalignment (two's-complement mod 4)
    const int baseAl = base - off;               // aligned load start (mult of 4)
    const int nV = (nOut + off + 3) >> 2;        // aligned float4s to stage (<= 1021)

    const float* __restrict__ xr = x + (size_t)b * (size_t)T;

    // ---- stage: issue all loads first (independent, stay in flight) ----
    float4 v[NITER];
#pragma unroll
    for (int n = 0; n < NITER; ++n) {
        const int k = t + n * 256;
        if (k < nV) {
            int src = baseAl + 4 * k;
            if (src < 0) src += T;
            else if (src >= T) src -= T;        // stays 16B-aligned (T % 4 == 0)
            v[n] = *reinterpret_cast<const float4*>(xr + src);
        }
    }
    // ---- drain into padded LDS ----
#pragma unroll
    for (int n = 0; n < NITER; ++n) {
        const int k = t + n * 256;
        if (k < nV) {
            const int i = 4 * k;                 // pad(4k..4k+3) = 5k..5k+3
            lds[5 * k + 0] = v[n].x;
            lds[5 * k + 1] = v[n].y;
            lds[5 * k + 2] = v[n].z;
            lds[5 * k + 3] = v[n].w;
        }
    }
    __syncthreads();

    // ---- realign: padded LDS reads -> aligned float4 stores ----
    float* __restrict__ orow = out + (size_t)b * (size_t)T + chunk0;
#pragma unroll
    for (int n = 0; n < NITER; ++n) {
        const int j = 4 * (t + n * 256);         // output offset within chunk
        if (j < nOut) {
            const int i = off + j;               // staged index of first float
            float4 o;
            o.x = lds[pad(i + 0)];
            o.y = lds[pad(i + 1)];
            o.z = lds[pad(i + 2)];
            o.w = lds[pad(i + 3)];
            *reinterpret_cast<float4*>(orow + j) = o;
        }
    }
}

// Generic scalar fallback (T not divisible by 4).
__global__ void roll_rows_scalar(const float* __restrict__ x,
                                 const int* __restrict__ shifts,
                                 float* __restrict__ out,
                                 int T) {
    const int b = blockIdx.y;
    const int j = blockIdx.x * blockDim.x + threadIdx.x;
    if (j >= T) return;
    int s = shifts[b] % T;
    if (s < 0) s += T;
    int i = j - s;
    if (i < 0) i += T;
    out[(size_t)b * T + j] = x[(size_t)b * T + i];
}

extern "C" void kernel_launch(void* const* d_in, const int* in_sizes, int n_in,
                              void* d_out, int out_size, void* d_ws, size_t ws_size,
                              hipStream_t stream) {
    const float* x = (const float*)d_in[0];
    const int* shifts = (const int*)d_in[1];
    float* out = (float*)d_out;

    const int B = in_sizes[1];
    const int T = in_sizes[0] / B;

    if ((T & 3) == 0) {
        dim3 block(256);
        dim3 grid((T + CHUNK - 1) / CHUNK, B);
        roll_rows_lds<<<grid, block, 0, stream>>>(x, shifts, out, T);
    } else {
        dim3 block(256);
        dim3 grid((T + 255) / 256, B);
        roll_rows_scalar<<<grid, block, 0, stream>>>(x, shifts, out, T);
    }
}